// Round 10
// baseline (115.499 us; speedup 1.0000x reference)
//
#include <hip/hip_runtime.h>
#include <math.h>

#define HH 512
#define WW 512
#define NTOT (64u*512u*512u)
#define NBLK 1024
#define TS 128          // output tile edge
#define TROWS 132       // TS + 4 halo rows
#define TCH 18          // 8-wide chunks per row (144 cols: gx in [bx-8, bx+136))
#define NTASK (TROWS*TCH)   // 2376
#define NTASKP 2432         // NTASK rounded up to whole waves (38 x 64)
#define NITER 10            // ceil(NTASK/256)

typedef __attribute__((ext_vector_type(8))) short short8;
typedef __attribute__((ext_vector_type(4))) float f32x4;

__device__ __forceinline__ float fsqrtf(float x) { return __builtin_amdgcn_sqrtf(x); }

__device__ __forceinline__ float shrinkf(float x, float l) {
    float a = x - l, b = x + l;
    return x + 0.5f * (fsqrtf(__builtin_fmaf(a, a, 1.f)) - fsqrtf(__builtin_fmaf(b, b, 1.f)));
}

__device__ __forceinline__ float bf2f(unsigned int u) {
    union { unsigned int i; float f; } cv;
    cv.i = u << 16;
    return cv.f;
}
__device__ __forceinline__ float lo2f(unsigned int p) {
    union { unsigned int i; float f; } cv; cv.i = p << 16; return cv.f;
}
__device__ __forceinline__ float hi2f(unsigned int p) {
    union { unsigned int i; float f; } cv; cv.i = p & 0xffff0000u; return cv.f;
}

// v_cvt_pk_bf16_f32 (RNE): dst = bf16(lo) | (bf16(hi) << 16)
__device__ __forceinline__ unsigned int cvtpk(float lo, float hi) {
    unsigned int r;
    asm("v_cvt_pk_bf16_f32 %0, %1, %2" : "=v"(r) : "v"(lo), "v"(hi));
    return r;
}

__device__ __forceinline__ void bf8(uint4 u, float* f) {
    f[0] = bf2f(u.x & 0xffffu); f[1] = bf2f(u.x >> 16);
    f[2] = bf2f(u.y & 0xffffu); f[3] = bf2f(u.y >> 16);
    f[4] = bf2f(u.z & 0xffffu); f[5] = bf2f(u.z >> 16);
    f[6] = bf2f(u.w & 0xffffu); f[7] = bf2f(u.w >> 16);
}

// async global->LDS, 16 B per lane; LDS dest = wave-uniform base + lane*16
__device__ __forceinline__ void gload16(const unsigned short* g, unsigned short* l) {
    __builtin_amdgcn_global_load_lds(
        (const __attribute__((address_space(1))) void*)g,
        (__attribute__((address_space(3))) void*)l,
        16, 0, 0);
}

// MFMA conv (Toeplitz): out[ct] += sum_ky A_ky(16x32) x B_ky(32x16)
//   A_ky[m][k] = tile[row0+m+ky][ct*16 + k]  (tile col t <-> gx = bx + t - 8)
//   B_ky[k][n] = w[ky][k-n-6] if 0 <= k-n-6 <= 4 else 0
// MODE 0: y (fp32) identity -> t1 bf16           (register-prefetch staging)
// MODE 1: t1, shrink(n1(t1), l0) -> t2 bf16      (global_load_lds staging)
// MODE 2: t1,t2, shrink(n2+n1, l1) -> t3/out     (global_load_lds staging x2)
template <int MODE, bool OBF>
__global__ __launch_bounds__(256, (MODE == 2 ? 2 : 4)) void conv_k(
    const float* __restrict__ yin,
    const unsigned short* __restrict__ t1,
    const unsigned short* __restrict__ t2,
    unsigned short* __restrict__ outbf,
    float* __restrict__ outf32,
    const float* __restrict__ wgt,
    const float* __restrict__ bias,
    const float* __restrict__ stats,
    const float* __restrict__ lambd,
    float* __restrict__ partials)
{
    constexpr int TP_ = (MODE == 0) ? 152 : 144;   // LDS pitch in bf16
    constexpr int TILE_SH = (MODE == 0) ? (TROWS * 152) : (NTASKP * 8);
    __shared__ unsigned short tile[TILE_SH];
    __shared__ unsigned short raw2[(MODE == 2) ? NTASKP * 8 : 8];

    const int tid = threadIdx.x;
    const int by = blockIdx.y * TS;
    const int bx = blockIdx.x * TS;
    const size_t ibase = (size_t)blockIdx.z * (HH * WW);

    float s1 = 0.f, h1 = 0.f, s2v = 0.f, h2 = 0.f, lam = 0.f;
    if constexpr (MODE == 1) { s1 = stats[0]; h1 = stats[1]; lam = lambd[0]; }
    if constexpr (MODE == 2) {
        s1 = stats[0]; h1 = stats[1]; s2v = stats[2]; h2 = stats[3]; lam = lambd[1];
    }

    // uniform weights -> SGPRs
    float wloc[25];
#pragma unroll
    for (int i = 0; i < 25; i++) wloc[i] = wgt[i];

    // ---- lane-local B fragments (no LDS): lane holds B[k=kb*8+j][n=lm] ----
    const int lane = tid & 63;
    const int lm = lane & 15;
    const int kb = lane >> 4;
    const int basei = kb * 8 - lm - 6;   // idx = basei + j, valid 0..4
    short8 bfr[5];
#pragma unroll
    for (int ky = 0; ky < 5; ky++) {
        unsigned pkw[4];
#pragma unroll
        for (int jj = 0; jj < 4; jj++) {
            float v0 = 0.f, v1 = 0.f;
            const int i0 = basei + 2 * jj, i1 = i0 + 1;
#pragma unroll
            for (int t = 0; t < 5; t++) {
                if (i0 == t) v0 = wloc[ky * 5 + t];
                if (i1 == t) v1 = wloc[ky * 5 + t];
            }
            pkw[jj] = cvtpk(v0, v1);
        }
        union { unsigned u[4]; short8 s; } cv;
        cv.u[0] = pkw[0]; cv.u[1] = pkw[1]; cv.u[2] = pkw[2]; cv.u[3] = pkw[3];
        bfr[ky] = cv.s;
    }

    if constexpr (MODE == 0) {
        // ---- register-prefetch staging (proven, at BW floor for y) ----
        uint4 curA = make_uint4(0u,0u,0u,0u), curB = make_uint4(0u,0u,0u,0u);
        {
            const int task = tid;
            const int row = task / TCH;
            const int ch  = task - row * TCH;
            const int gy  = by + row - 2;
            const int gx0 = bx + ch * 8 - 8;
            if (gy >= 0 && gy < HH && gx0 >= 0 && gx0 <= WW - 8) {
                const size_t g = ibase + (size_t)gy * WW + gx0;
                curA = *(const uint4*)(yin + g);
                curB = *(const uint4*)(yin + g + 4);
            }
        }
#pragma unroll
        for (int t = 0; t < NITER; t++) {
            uint4 nxtA = make_uint4(0u,0u,0u,0u), nxtB = make_uint4(0u,0u,0u,0u);
            if (t + 1 < NITER) {
                const int ntsk = tid + (t + 1) * 256;
                const int row = ntsk / TCH;
                const int ch  = ntsk - row * TCH;
                const int gy  = by + row - 2;
                const int gx0 = bx + ch * 8 - 8;
                if (ntsk < NTASK && gy >= 0 && gy < HH && gx0 >= 0 && gx0 <= WW - 8) {
                    const size_t g = ibase + (size_t)gy * WW + gx0;
                    nxtA = *(const uint4*)(yin + g);
                    nxtB = *(const uint4*)(yin + g + 4);
                }
            }
            const int task = tid + t * 256;
            if (task < NTASK) {
                const int row = task / TCH;
                const int ch  = task - row * TCH;
                uint4 pk = make_uint4(0u,0u,0u,0u);
                const float4 a = *(const float4*)&curA;
                const float4 b = *(const float4*)&curB;
                pk.x = cvtpk(a.x, a.y); pk.y = cvtpk(a.z, a.w);
                pk.z = cvtpk(b.x, b.y); pk.w = cvtpk(b.z, b.w);
                const int gy  = by + row - 2;
                const int gx0 = bx + ch * 8 - 8;
                if (!(gy >= 0 && gy < HH && gx0 >= 0 && gx0 <= WW - 8))
                    pk = make_uint4(0u,0u,0u,0u);
                *(uint4*)&tile[row * TP_ + ch * 8] = pk;
            }
            curA = nxtA; curB = nxtB;
        }
    } else {
        // ---- async staging: all chunk loads in flight via global_load_lds ----
        // GUARD (round-9 bugfix): only issue waves whose first task < NTASK,
        // so the max written slot is NTASKP-1 (wave-uniform branch, no
        // divergence; partial-wave lanes load dummy src into never-read slots).
        const int wv4 = tid >> 6;
#pragma unroll
        for (int r = 0; r < NITER; r++) {
            const int task0 = r * 256 + wv4 * 64;
            if (task0 < NTASK) {
                const int task = task0 + lane;
                const int row = task / TCH;
                const int ch  = task - row * TCH;
                const int gy  = by + row - 2;
                const int gx0 = bx + ch * 8 - 8;
                const bool ok = (task < NTASK) && gy >= 0 && gy < HH &&
                                gx0 >= 0 && gx0 <= WW - 8;
                const size_t g = ok ? (ibase + (size_t)gy * WW + gx0) : ibase;
                gload16(t1 + g, &tile[task * 8]);         // linear dest: task*16 B
                if constexpr (MODE == 2)
                    gload16(t2 + g, &raw2[task * 8]);
            }
        }
        __syncthreads();   // drains vmcnt(0): all LDS data landed

        // ---- in-place elementwise transform (race-free per 16-B chunk) ----
#pragma unroll
        for (int t = 0; t < NITER; t++) {
            const int task = tid + t * 256;
            if (task < NTASK) {
                const int row = task / TCH;
                const int ch  = task - row * TCH;
                const int gy  = by + row - 2;
                const int gx0 = bx + ch * 8 - 8;
                const bool ok = gy >= 0 && gy < HH && gx0 >= 0 && gx0 <= WW - 8;
                uint4 pk = make_uint4(0u,0u,0u,0u);
                if (ok) {
                    uint4 u1 = *(const uint4*)&tile[task * 8];
                    float f1[8]; bf8(u1, f1);
                    float v[8];
                    if constexpr (MODE == 1) {
#pragma unroll
                        for (int k = 0; k < 8; k++)
                            v[k] = shrinkf(__builtin_fmaf(f1[k], s1, h1), lam);
                    } else {
                        uint4 u2 = *(const uint4*)&raw2[task * 8];
                        float f2[8]; bf8(u2, f2);
#pragma unroll
                        for (int k = 0; k < 8; k++) {
                            float x = __builtin_fmaf(f2[k], s2v, h2)
                                    + __builtin_fmaf(f1[k], s1, h1);
                            v[k] = shrinkf(x, lam);
                        }
                    }
                    pk.x = cvtpk(v[0], v[1]); pk.y = cvtpk(v[2], v[3]);
                    pk.z = cvtpk(v[4], v[5]); pk.w = cvtpk(v[6], v[7]);
                }
                *(uint4*)&tile[task * 8] = pk;   // OOB -> literal zero
            }
        }
    }

    const float b0 = bias[0];
    __syncthreads();

    // ---- MFMA phase: wave wv owns 32 output rows x 128 cols ----
    const int wv = tid >> 6;
    const int r0w = wv * 32;

    f32x4 acc[2][8];
#pragma unroll
    for (int st = 0; st < 2; st++)
#pragma unroll
        for (int ct = 0; ct < 8; ct++)
            acc[st][ct] = (f32x4){0.f, 0.f, 0.f, 0.f};

#pragma unroll
    for (int ky = 0; ky < 5; ky++) {
        const short8 b = bfr[ky];
#pragma unroll
        for (int st = 0; st < 2; st++) {
            const unsigned short* ab = &tile[(r0w + st * 16 + lm + ky) * TP_ + kb * 8];
#pragma unroll
            for (int ct = 0; ct < 8; ct++) {
                short8 a = *(const short8*)(ab + ct * 16);
                acc[st][ct] = __builtin_amdgcn_mfma_f32_16x16x32_bf16(a, b, acc[st][ct], 0, 0, 0);
            }
        }
    }

    // ---- epilogue: lane holds rows kb*4+e, col lm of each 16x16 tile ----
    float s = 0.f, q = 0.f;
#pragma unroll
    for (int st = 0; st < 2; st++) {
#pragma unroll
        for (int ct = 0; ct < 8; ct++) {
            const f32x4 a = acc[st][ct];
            const int grow0 = by + r0w + st * 16 + kb * 4;
            const size_t base = ibase + (size_t)grow0 * WW + bx + ct * 16 + lm;
            if constexpr (OBF) {
                unsigned p01 = cvtpk(a[0] + b0, a[1] + b0);
                unsigned p23 = cvtpk(a[2] + b0, a[3] + b0);
                outbf[base]          = (unsigned short)(p01 & 0xffffu);
                outbf[base + WW]     = (unsigned short)(p01 >> 16);
                outbf[base + 2 * WW] = (unsigned short)(p23 & 0xffffu);
                outbf[base + 3 * WW] = (unsigned short)(p23 >> 16);
                float fr0 = lo2f(p01), fr1 = hi2f(p01), fr2 = lo2f(p23), fr3 = hi2f(p23);
                s += fr0 + fr1 + fr2 + fr3;
                q = __builtin_fmaf(fr0, fr0, __builtin_fmaf(fr1, fr1,
                    __builtin_fmaf(fr2, fr2, __builtin_fmaf(fr3, fr3, q))));
            } else {
                float f0 = a[0] + b0, f1v = a[1] + b0, f2v = a[2] + b0, f3v = a[3] + b0;
                outf32[base]          = f0;
                outf32[base + WW]     = f1v;
                outf32[base + 2 * WW] = f2v;
                outf32[base + 3 * WW] = f3v;
                s += f0 + f1v + f2v + f3v;
                q = __builtin_fmaf(f0, f0, __builtin_fmaf(f1v, f1v,
                    __builtin_fmaf(f2v, f2v, __builtin_fmaf(f3v, f3v, q))));
            }
        }
    }

    // ---- block reduction (LDS tree, reuse tile) ----
    __syncthreads();
    float* red = (float*)tile;
    red[tid] = s; red[256 + tid] = q;
    __syncthreads();
    for (int off = 128; off > 0; off >>= 1) {
        if (tid < off) { red[tid] += red[tid + off]; red[256 + tid] += red[256 + tid + off]; }
        __syncthreads();
    }
    if (tid == 0) {
        const int bid = (blockIdx.z * 4 + blockIdx.y) * 4 + blockIdx.x;
        partials[bid * 2] = red[0];
        partials[bid * 2 + 1] = red[256];
    }
}

__global__ __launch_bounds__(256) void finalize_k(
    const float* __restrict__ partials, float* __restrict__ stats, int stage,
    const float* __restrict__ gamma, const float* __restrict__ beta)
{
    __shared__ double rs[256], rq[256];
    const int tid = threadIdx.x;
    double s = 0.0, q = 0.0;
    for (int i = tid; i < NBLK; i += 256) { s += partials[2 * i]; q += partials[2 * i + 1]; }
    rs[tid] = s; rq[tid] = q;
    __syncthreads();
    for (int off = 128; off > 0; off >>= 1) {
        if (tid < off) { rs[tid] += rs[tid + off]; rq[tid] += rq[tid + off]; }
        __syncthreads();
    }
    if (tid == 0) {
        double mean = rs[0] / (double)NTOT;
        double var = rq[0] / (double)NTOT - mean * mean;
        double scl = (double)gamma[0] / sqrt(var + 1e-5);
        stats[2 * stage] = (float)scl;
        stats[2 * stage + 1] = (float)((double)beta[0] - mean * scl);
    }
}

// out = shrink(n3(t3) + n1(t1), lambd[2]); t3 bf16 (T3BF) or fp32 in io
template <bool T3BF>
__global__ __launch_bounds__(256) void final_k(
    const unsigned short* __restrict__ t1,
    const unsigned short* __restrict__ t3b,
    float* __restrict__ io,
    const float* __restrict__ stats, const float* __restrict__ lambd)
{
    const float s1 = stats[0], h1 = stats[1], s3 = stats[4], h3 = stats[5];
    const float lam = lambd[2];
    const size_t base = ((size_t)blockIdx.x * 256 + threadIdx.x) * 8;

    uint4 u1 = *(const uint4*)(t1 + base);
    float f1[8]; bf8(u1, f1);

    float t3v[8];
    if constexpr (T3BF) {
        uint4 u3 = *(const uint4*)(t3b + base);
        bf8(u3, t3v);
    } else {
        float4 a0 = *(const float4*)(io + base);
        float4 a1 = *(const float4*)(io + base + 4);
        t3v[0]=a0.x; t3v[1]=a0.y; t3v[2]=a0.z; t3v[3]=a0.w;
        t3v[4]=a1.x; t3v[5]=a1.y; t3v[6]=a1.z; t3v[7]=a1.w;
    }

    float r[8];
#pragma unroll
    for (int k = 0; k < 8; k++) {
        float v = __builtin_fmaf(t3v[k], s3, h3) + __builtin_fmaf(f1[k], s1, h1);
        r[k] = shrinkf(v, lam);
    }
    *(float4*)(io + base)     = make_float4(r[0], r[1], r[2], r[3]);
    *(float4*)(io + base + 4) = make_float4(r[4], r[5], r[6], r[7]);
}

extern "C" void kernel_launch(void* const* d_in, const int* in_sizes, int n_in,
                              void* d_out, int out_size, void* d_ws, size_t ws_size,
                              hipStream_t stream)
{
    const float* y     = (const float*)d_in[0];
    const float* wgt   = (const float*)d_in[1];
    const float* bias  = (const float*)d_in[2];
    const float* gamma = (const float*)d_in[3];
    const float* beta  = (const float*)d_in[4];
    const float* lambd = (const float*)d_in[5];
    float* out = (float*)d_out;

    char* ws = (char*)d_ws;
    unsigned short* t1 = (unsigned short*)ws;                    // 33,554,432 B
    unsigned short* t2 = (unsigned short*)(ws + 33554432ull);    // 33,554,432 B
    unsigned short* t3 = (unsigned short*)(ws + 67108864ull);    // 33,554,432 B
    const bool t3bf = (ws_size >= 100696088ull);
    const size_t poff = t3bf ? 100663296ull : 67108864ull;
    float* partials = (float*)(ws + poff);                       // 8,192 B used
    float* stats    = (float*)(ws + poff + 32768ull);            // 24 B

    dim3 grid(4, 4, 64), blk(256);
    conv_k<0, true><<<grid, blk, 0, stream>>>(y, nullptr, nullptr, t1, nullptr,
                                              wgt, bias, stats, lambd, partials);
    finalize_k<<<1, blk, 0, stream>>>(partials, stats, 0, gamma, beta);
    conv_k<1, true><<<grid, blk, 0, stream>>>(nullptr, t1, nullptr, t2, nullptr,
                                              wgt, bias, stats, lambd, partials);
    finalize_k<<<1, blk, 0, stream>>>(partials, stats, 1, gamma, beta);
    if (t3bf) {
        conv_k<2, true><<<grid, blk, 0, stream>>>(nullptr, t1, t2, t3, nullptr,
                                                  wgt, bias, stats, lambd, partials);
        finalize_k<<<1, blk, 0, stream>>>(partials, stats, 2, gamma, beta);
        final_k<true><<<8192, blk, 0, stream>>>(t1, t3, out, stats, lambd);
    } else {
        conv_k<2, false><<<grid, blk, 0, stream>>>(nullptr, t1, t2, nullptr, out,
                                                   wgt, bias, stats, lambd, partials);
        finalize_k<<<1, blk, 0, stream>>>(partials, stats, 2, gamma, beta);
        final_k<false><<<8192, blk, 0, stream>>>(t1, nullptr, out, stats, lambd);
    }
}